// Round 1
// baseline (72.466 us; speedup 1.0000x reference)
//
#include <hip/hip_runtime.h>

// Problem geometry (fixed by the reference): B=4096, T=1024, D=6.
#define NROWS (4096 * 1024)        // B*T rows of 6 floats
#define NPAIRS (NROWS / 2)         // process 2 rows (12 floats / 3x float4) per iter
#define NELEM_PER_CAT (NROWS * 3)  // denominator for each mean (B*T*3)

__device__ __forceinline__ float norm_angle(float a) {
    const float PI     = 3.14159265358979323846f;
    const float TWO_PI = 6.28318530717958647692f;
    a = (a >  PI) ? a - TWO_PI : a;
    a = (a < -PI) ? a + TWO_PI : a;
    return a;
}

__global__ void wmse_init_kernel(double* acc) {
    if (threadIdx.x < 2) acc[threadIdx.x] = 0.0;
}

__global__ void __launch_bounds__(256) wmse_main_kernel(
        const float4* __restrict__ pred, const float4* __restrict__ targ,
        double* __restrict__ acc) {
    float ts = 0.0f, rs = 0.0f;
    const int stride = gridDim.x * blockDim.x;
    for (int p = blockIdx.x * blockDim.x + threadIdx.x; p < NPAIRS; p += stride) {
        // 2 rows = channels [0,1,2,3 | 4,5,0,1 | 2,3,4,5]
        float4 p0 = pred[3 * p + 0], p1 = pred[3 * p + 1], p2 = pred[3 * p + 2];
        float4 t0 = targ[3 * p + 0], t1 = targ[3 * p + 1], t2 = targ[3 * p + 2];
        float d;
        d = p0.x - t0.x;                           ts += d * d;  // ch0
        d = p0.y - t0.y;                           ts += d * d;  // ch1
        d = p0.z - t0.z;                           ts += d * d;  // ch2
        d = norm_angle(p0.w) - norm_angle(t0.w);   rs += d * d;  // ch3
        d = norm_angle(p1.x) - norm_angle(t1.x);   rs += d * d;  // ch4
        d = norm_angle(p1.y) - norm_angle(t1.y);   rs += d * d;  // ch5
        d = p1.z - t1.z;                           ts += d * d;  // ch0
        d = p1.w - t1.w;                           ts += d * d;  // ch1
        d = p2.x - t2.x;                           ts += d * d;  // ch2
        d = norm_angle(p2.y) - norm_angle(t2.y);   rs += d * d;  // ch3
        d = norm_angle(p2.z) - norm_angle(t2.z);   rs += d * d;  // ch4
        d = norm_angle(p2.w) - norm_angle(t2.w);   rs += d * d;  // ch5
    }

    // wave64 butterfly reduce
    #pragma unroll
    for (int off = 32; off > 0; off >>= 1) {
        ts += __shfl_down(ts, off, 64);
        rs += __shfl_down(rs, off, 64);
    }
    __shared__ float sts[4], srs[4];
    const int wave = threadIdx.x >> 6, lane = threadIdx.x & 63;
    if (lane == 0) { sts[wave] = ts; srs[wave] = rs; }
    __syncthreads();
    if (threadIdx.x == 0) {
        float t = sts[0] + sts[1] + sts[2] + sts[3];
        float r = srs[0] + srs[1] + srs[2] + srs[3];
        atomicAdd(&acc[0], (double)t);
        atomicAdd(&acc[1], (double)r);
    }
}

__global__ void wmse_final_kernel(const double* __restrict__ acc, float* __restrict__ out) {
    if (threadIdx.x == 0) {
        double inv_n = 1.0 / (double)NELEM_PER_CAT;
        double trans = acc[0] * inv_n * 1.0;    // TRANS_WEIGHT
        double rot   = acc[1] * inv_n * 100.0;  // ROT_WEIGHT
        out[0] = (float)(trans + rot);  // total
        out[1] = (float)trans;
        out[2] = (float)rot;
    }
}

extern "C" void kernel_launch(void* const* d_in, const int* in_sizes, int n_in,
                              void* d_out, int out_size, void* d_ws, size_t ws_size,
                              hipStream_t stream) {
    const float4* pred = (const float4*)d_in[0];
    const float4* targ = (const float4*)d_in[1];
    double* acc = (double*)d_ws;
    float* out = (float*)d_out;

    wmse_init_kernel<<<1, 64, 0, stream>>>(acc);

    const int threads = 256;
    const int blocks = 2048;  // grid-stride: 4 pairs per thread
    wmse_main_kernel<<<blocks, threads, 0, stream>>>(pred, targ, acc);

    wmse_final_kernel<<<1, 64, 0, stream>>>(acc, out);
}